// Round 1
// baseline (861.209 us; speedup 1.0000x reference)
//
#include <hip/hip_runtime.h>
#include <hip/hip_bf16.h>

typedef __bf16 bf16_t;
typedef __bf16 bf16x8 __attribute__((ext_vector_type(8)));
typedef float f32x4 __attribute__((ext_vector_type(4)));

#define MFMA16(a, b, c) __builtin_amdgcn_mfma_f32_16x16x32_bf16((a), (b), (c), 0, 0, 0)

// Problem constants
#define BATCH 4096
#define SEQN 128
#define EVN 64
#define HN 256
#define G3 768
#define LEN_VN 1500
#define IPD_VN 256
#define NLABELS 100
#define TSTEPS 32

// Workspace layout (bytes, 256-aligned)
#define OFF_LENT   0u           // 1500*64*4 = 384000
#define OFF_IPDT   384000u      // 256*64*4  = 65536
#define OFF_BRZ    449536u      // 512*4     = 2048
#define OFF_WIH    451584u      // 768*256*2 = 393216
#define OFF_WHH    844800u      // 393216
#define OFF_RNN    1238016u     // 4096*32*256*2 = 67108864
#define WS_NEEDED  68346880u

__device__ __forceinline__ float sigf(float x) {
    return __builtin_amdgcn_rcpf(1.f + __expf(-x));
}
__device__ __forceinline__ float tanh_fast(float x) {
    return 2.f * __builtin_amdgcn_rcpf(1.f + __expf(-2.f * x)) - 1.f;
}

// ---------------------------------------------------------------------------
// K1: prep. blocks [0,439): fused embed+FC tables. [439,631): weight frags.
// [631,633): b_ih+b_hh (r,z part).
// ---------------------------------------------------------------------------
__global__ void prep_kernel(const float* __restrict__ len_emb,
                            const float* __restrict__ ipd_emb,
                            const float* __restrict__ fc_w,
                            const float* __restrict__ fc_b,
                            const float* __restrict__ w_ih,
                            const float* __restrict__ w_hh,
                            const float* __restrict__ b_ih,
                            const float* __restrict__ b_hh,
                            float* __restrict__ lenT, float* __restrict__ ipdT,
                            float* __restrict__ brz,
                            bf16_t* __restrict__ wfrag_ih,
                            bf16_t* __restrict__ wfrag_hh) {
    const int bid = blockIdx.x, tid = threadIdx.x;
    if (bid < 439) {
        const int row = bid * 4 + (tid >> 6);
        const int e = tid & 63;
        if (row < LEN_VN) {
            const float* emb = len_emb + row * 64;
            const float* wv = fc_w + e * 128;
            float s = fc_b[e];
            #pragma unroll 8
            for (int j = 0; j < 64; ++j) s += emb[j] * wv[j];
            lenT[row * 64 + e] = s;
        } else if (row < LEN_VN + IPD_VN) {
            const int v = row - LEN_VN;
            const float* emb = ipd_emb + v * 64;
            const float* wv = fc_w + e * 128 + 64;
            float s = 0.f;
            #pragma unroll 8
            for (int j = 0; j < 64; ++j) s += emb[j] * wv[j];
            ipdT[v * 64 + e] = s;
        }
    } else if (bid < 631) {
        // Fragment order: wfrag[c(48)][kt(8)][lane(64)][8], value =
        // W[c*16 + (lane&15)][kt*32 + (lane>>4)*8 + j]  (B-operand layout)
        const int flat = (bid - 439) * 256 + tid;   // 0..49151
        const int which = flat / 24576;
        const int rem = flat % 24576;
        const int c = rem >> 9;
        const int kt = (rem >> 6) & 7;
        const int lane = rem & 63;
        const int g = c * 16 + (lane & 15);
        const int k0 = kt * 32 + (lane >> 4) * 8;
        const float* src = (which == 0 ? w_ih : w_hh) + g * 256 + k0;
        bf16_t* dst = (which == 0 ? wfrag_ih : wfrag_hh) + ((c * 8 + kt) * 64 + lane) * 8;
        f32x4 s0 = *(const f32x4*)(src);
        f32x4 s1 = *(const f32x4*)(src + 4);
        bf16x8 o;
        #pragma unroll
        for (int j = 0; j < 4; ++j) { o[j] = (bf16_t)s0[j]; o[4 + j] = (bf16_t)s1[j]; }
        *(bf16x8*)dst = o;
    } else {
        const int g = (bid - 631) * 256 + tid;
        if (g < 512) brz[g] = b_ih[g] + b_hh[g];
    }
}

// ---------------------------------------------------------------------------
// K2: gather rnn_in into A-fragment order.
// rnnfrag[bt(128)][t(32)][m2(2)][kt(8)][lane(64)][8] =
//   rnn_in[bt*32 + m2*16 + (lane&15)][t][kt*32 + (lane>>4)*8 + j]
// where rnn_in[b][t][p*64+e] = lenT[len_x[b][4t+p]][e] + ipdT[ipd_x[b][4t+p]][e]
// ---------------------------------------------------------------------------
__global__ void gather_kernel(const int* __restrict__ len_x,
                              const int* __restrict__ ipd_x,
                              const float* __restrict__ lenT,
                              const float* __restrict__ ipdT,
                              bf16_t* __restrict__ rnnfrag) {
    const int flat = blockIdx.x * 256 + threadIdx.x;
    const int lane = flat & 63;
    const int kt = (flat >> 6) & 7;
    const int m2 = (flat >> 9) & 1;
    const int t = (flat >> 10) & 31;
    const int bt = flat >> 15;
    const int b = bt * 32 + m2 * 16 + (lane & 15);
    const int k0 = kt * 32 + (lane >> 4) * 8;
    const int p = k0 >> 6;
    const int e0 = k0 & 63;
    const int seq = t * 4 + p;
    const int v1 = len_x[b * SEQN + seq];
    const int v2 = ipd_x[b * SEQN + seq];
    const f32x4* lp = (const f32x4*)(lenT + v1 * 64 + e0);
    const f32x4* ip = (const f32x4*)(ipdT + v2 * 64 + e0);
    f32x4 a0 = lp[0] + ip[0];
    f32x4 a1 = lp[1] + ip[1];
    bf16x8 o;
    #pragma unroll
    for (int j = 0; j < 4; ++j) { o[j] = (bf16_t)a0[j]; o[4 + j] = (bf16_t)a1[j]; }
    *(bf16x8*)(rnnfrag + (size_t)flat * 8) = o;
}

// ---------------------------------------------------------------------------
// K3: fused GRU. 128 blocks x 512 threads (8 waves). Block owns 32 batch rows.
// Wave w owns hidden units [32w, 32w+32): r-tiles {2w,2w+1}, z {16+..}, n {32+..}.
// h kept fp32 in registers (C-frag layout) + bf16 A-frag copy in LDS.
// ---------------------------------------------------------------------------
__global__ void __launch_bounds__(512, 2)
gru_kernel(const bf16_t* __restrict__ rnnfrag,
           const bf16_t* __restrict__ wfrag_ih,
           const bf16_t* __restrict__ wfrag_hh,
           const float* __restrict__ brz,
           const float* __restrict__ b_ih,
           const float* __restrict__ b_hh,
           const float* __restrict__ out_w,
           const float* __restrict__ out_b,
           float* __restrict__ out) {
    __shared__ bf16_t h_lds[2 * 8 * 64 * 8];   // 16 KB, A-frag order
    __shared__ float h_fin[32 * 260];          // final h, padded stride

    const int tid = threadIdx.x;
    const int lane = tid & 63;
    const int w = tid >> 6;
    const int bt = blockIdx.x;
    const int col = lane & 15;
    const int jbase = w * 32;

    // zero initial h
    for (int i = tid; i < 2 * 8 * 64 * 8; i += 512) h_lds[i] = (bf16_t)0.f;

    // biases for this lane's gate columns
    const float b_r0 = brz[jbase + col];
    const float b_r1 = brz[jbase + 16 + col];
    const float b_z0 = brz[256 + jbase + col];
    const float b_z1 = brz[256 + jbase + 16 + col];
    const float b_in0 = b_ih[512 + jbase + col];
    const float b_in1 = b_ih[512 + jbase + 16 + col];
    const float b_hn0 = b_hh[512 + jbase + col];
    const float b_hn1 = b_hh[512 + jbase + 16 + col];

    f32x4 hprev[2][2] = {};   // [c2][m2], fp32 h in C-frag layout

    const bf16_t* wih = wfrag_ih + lane * 8;
    const bf16_t* whh = wfrag_hh + lane * 8;
    const bf16_t* xbase = rnnfrag + (size_t)bt * (TSTEPS * 8192) + lane * 8;

    for (int t = 0; t < TSTEPS; ++t) {
        f32x4 acc_r[2][2] = {};
        f32x4 acc_z[2][2] = {};
        f32x4 acc_in[2][2] = {};
        f32x4 acc_hn[2][2] = {};

        __syncthreads();   // h_lds writes from t-1 (or init) visible

        const bf16_t* xt = xbase + (size_t)t * 8192;
        #pragma unroll
        for (int kt = 0; kt < 8; ++kt) {
            bf16x8 ax0 = *(const bf16x8*)(xt + kt * 512);
            bf16x8 ax1 = *(const bf16x8*)(xt + 4096 + kt * 512);
            bf16x8 ah0 = *(const bf16x8*)(&h_lds[kt * 512 + lane * 8]);
            bf16x8 ah1 = *(const bf16x8*)(&h_lds[4096 + kt * 512 + lane * 8]);
            #pragma unroll
            for (int c2 = 0; c2 < 2; ++c2) {
                const int cr = 2 * w + c2;
                const int cz = 16 + 2 * w + c2;
                const int cn = 32 + 2 * w + c2;
                bf16x8 f_ir = *(const bf16x8*)(wih + (cr * 8 + kt) * 512);
                bf16x8 f_hr = *(const bf16x8*)(whh + (cr * 8 + kt) * 512);
                bf16x8 f_iz = *(const bf16x8*)(wih + (cz * 8 + kt) * 512);
                bf16x8 f_hz = *(const bf16x8*)(whh + (cz * 8 + kt) * 512);
                bf16x8 f_in = *(const bf16x8*)(wih + (cn * 8 + kt) * 512);
                bf16x8 f_hn = *(const bf16x8*)(whh + (cn * 8 + kt) * 512);
                acc_r[c2][0] = MFMA16(ax0, f_ir, acc_r[c2][0]);
                acc_r[c2][1] = MFMA16(ax1, f_ir, acc_r[c2][1]);
                acc_r[c2][0] = MFMA16(ah0, f_hr, acc_r[c2][0]);
                acc_r[c2][1] = MFMA16(ah1, f_hr, acc_r[c2][1]);
                acc_z[c2][0] = MFMA16(ax0, f_iz, acc_z[c2][0]);
                acc_z[c2][1] = MFMA16(ax1, f_iz, acc_z[c2][1]);
                acc_z[c2][0] = MFMA16(ah0, f_hz, acc_z[c2][0]);
                acc_z[c2][1] = MFMA16(ah1, f_hz, acc_z[c2][1]);
                acc_in[c2][0] = MFMA16(ax0, f_in, acc_in[c2][0]);
                acc_in[c2][1] = MFMA16(ax1, f_in, acc_in[c2][1]);
                acc_hn[c2][0] = MFMA16(ah0, f_hn, acc_hn[c2][0]);
                acc_hn[c2][1] = MFMA16(ah1, f_hn, acc_hn[c2][1]);
            }
        }

        __syncthreads();   // all waves done reading h_lds

        #pragma unroll
        for (int c2 = 0; c2 < 2; ++c2) {
            const float brv = c2 ? b_r1 : b_r0;
            const float bzv = c2 ? b_z1 : b_z0;
            const float binv = c2 ? b_in1 : b_in0;
            const float bhnv = c2 ? b_hn1 : b_hn0;
            const int j = jbase + c2 * 16 + col;       // hidden index
            const int kt_j = j >> 5;
            const int lane_j = ((j >> 3) & 3) * 16;
            const int jj = j & 7;
            #pragma unroll
            for (int m2 = 0; m2 < 2; ++m2) {
                #pragma unroll
                for (int r = 0; r < 4; ++r) {
                    float rg = sigf(acc_r[c2][m2][r] + brv);
                    float zg = sigf(acc_z[c2][m2][r] + bzv);
                    float u = acc_in[c2][m2][r] + binv + rg * (acc_hn[c2][m2][r] + bhnv);
                    float ng = tanh_fast(u);
                    float hn = (1.f - zg) * ng + zg * hprev[c2][m2][r];
                    hprev[c2][m2][r] = hn;
                    const int m = ((lane >> 4) << 2) + r;
                    h_lds[(m2 * 8 + kt_j) * 512 + (lane_j + m) * 8 + jj] = (bf16_t)hn;
                }
            }
        }
    }

    // Final h -> LDS fp32, then logits = h @ out_w.T + out_b (fp32)
    #pragma unroll
    for (int c2 = 0; c2 < 2; ++c2) {
        const int j = jbase + c2 * 16 + col;
        #pragma unroll
        for (int m2 = 0; m2 < 2; ++m2) {
            #pragma unroll
            for (int r = 0; r < 4; ++r) {
                const int m = m2 * 16 + ((lane >> 4) << 2) + r;
                h_fin[m * 260 + j] = hprev[c2][m2][r];
            }
        }
    }
    __syncthreads();

    for (int i = tid; i < 32 * NLABELS; i += 512) {
        const int row = i / NLABELS;
        const int cl = i - row * NLABELS;
        const f32x4* wr = (const f32x4*)(out_w + cl * 256);
        const f32x4* hr = (const f32x4*)(h_fin + row * 260);
        f32x4 acc = {0.f, 0.f, 0.f, 0.f};
        #pragma unroll 4
        for (int k = 0; k < 64; ++k) acc += hr[k] * wr[k];
        out[(bt * 32 + row) * NLABELS + cl] =
            out_b[cl] + acc[0] + acc[1] + acc[2] + acc[3];
    }
}

// ---------------------------------------------------------------------------
extern "C" void kernel_launch(void* const* d_in, const int* in_sizes, int n_in,
                              void* d_out, int out_size, void* d_ws, size_t ws_size,
                              hipStream_t stream) {
    (void)in_sizes; (void)n_in; (void)out_size; (void)ws_size;
    const int*   len_x   = (const int*)d_in[0];
    const int*   ipd_x   = (const int*)d_in[1];
    const float* len_emb = (const float*)d_in[2];
    const float* ipd_emb = (const float*)d_in[3];
    const float* fc_w    = (const float*)d_in[4];
    const float* fc_b    = (const float*)d_in[5];
    const float* w_ih    = (const float*)d_in[6];
    const float* w_hh    = (const float*)d_in[7];
    const float* b_ih    = (const float*)d_in[8];
    const float* b_hh    = (const float*)d_in[9];
    const float* out_w   = (const float*)d_in[10];
    const float* out_b   = (const float*)d_in[11];

    char* ws = (char*)d_ws;
    float*  lenT = (float*)(ws + OFF_LENT);
    float*  ipdT = (float*)(ws + OFF_IPDT);
    float*  brz  = (float*)(ws + OFF_BRZ);
    bf16_t* wfi  = (bf16_t*)(ws + OFF_WIH);
    bf16_t* wfh  = (bf16_t*)(ws + OFF_WHH);
    bf16_t* rnn  = (bf16_t*)(ws + OFF_RNN);

    prep_kernel<<<633, 256, 0, stream>>>(len_emb, ipd_emb, fc_w, fc_b,
                                         w_ih, w_hh, b_ih, b_hh,
                                         lenT, ipdT, brz, wfi, wfh);
    gather_kernel<<<16384, 256, 0, stream>>>(len_x, ipd_x, lenT, ipdT, rnn);
    gru_kernel<<<128, 512, 0, stream>>>(rnn, wfi, wfh, brz, b_ih, b_hh,
                                        out_w, out_b, (float*)d_out);
}

// Round 2
// 264.924 us; speedup vs baseline: 3.2508x; 3.2508x over previous
//
#include <hip/hip_runtime.h>
#include <hip/hip_bf16.h>

typedef __bf16 bf16_t;
typedef __bf16 bf16x8 __attribute__((ext_vector_type(8)));
typedef float f32x4 __attribute__((ext_vector_type(4)));
typedef unsigned short u16x4 __attribute__((ext_vector_type(4)));

#define MFMA16(a, b, c) __builtin_amdgcn_mfma_f32_16x16x32_bf16((a), (b), (c), 0, 0, 0)

// Problem constants
#define BATCH 4096
#define SEQN 128
#define HN 256
#define NLABELS 100
#define TSTEPS 32
#define LEN_VN 1500
#define IPD_VN 256

// Workspace layout (bytes, 256-aligned)
#define OFF_LENT   0u           // 1500*64*4 = 384000
#define OFF_IPDT   384000u      // 256*64*4  = 65536
#define OFF_BRZ    449536u      // 512*4     = 2048
#define OFF_WIH    451584u      // 768*256*2 = 393216
#define OFF_WHH    844800u      // 393216
#define OFF_GI     1238016u     // 4096*32*768*2 = 201326592
#define WS_NEEDED  202564608u

__device__ __forceinline__ float sigf(float x) {
    return __builtin_amdgcn_rcpf(1.f + __expf(-x));
}
__device__ __forceinline__ float tanh_fast(float x) {
    return 2.f * __builtin_amdgcn_rcpf(1.f + __expf(-2.f * x)) - 1.f;
}
__device__ __forceinline__ float b2f(unsigned short v) {
    union { unsigned u; float f; } c; c.u = ((unsigned)v) << 16; return c.f;
}
__device__ __forceinline__ unsigned short f2b(float f) {
    union { bf16_t h; unsigned short s; } c; c.h = (bf16_t)f; return c.s;
}

// ---------------------------------------------------------------------------
// K1: prep. blocks [0,439): fused embed+FC tables. [439,631): weight frags.
// [631,633): b_ih+b_hh (r,z part).
// ---------------------------------------------------------------------------
__global__ void prep_kernel(const float* __restrict__ len_emb,
                            const float* __restrict__ ipd_emb,
                            const float* __restrict__ fc_w,
                            const float* __restrict__ fc_b,
                            const float* __restrict__ w_ih,
                            const float* __restrict__ w_hh,
                            const float* __restrict__ b_ih,
                            const float* __restrict__ b_hh,
                            float* __restrict__ lenT, float* __restrict__ ipdT,
                            float* __restrict__ brz,
                            bf16_t* __restrict__ wfrag_ih,
                            bf16_t* __restrict__ wfrag_hh) {
    const int bid = blockIdx.x, tid = threadIdx.x;
    if (bid < 439) {
        const int row = bid * 4 + (tid >> 6);
        const int e = tid & 63;
        if (row < LEN_VN) {
            const float* emb = len_emb + row * 64;
            const float* wv = fc_w + e * 128;
            float s = fc_b[e];
            #pragma unroll 8
            for (int j = 0; j < 64; ++j) s += emb[j] * wv[j];
            lenT[row * 64 + e] = s;
        } else if (row < LEN_VN + IPD_VN) {
            const int v = row - LEN_VN;
            const float* emb = ipd_emb + v * 64;
            const float* wv = fc_w + e * 128 + 64;
            float s = 0.f;
            #pragma unroll 8
            for (int j = 0; j < 64; ++j) s += emb[j] * wv[j];
            ipdT[v * 64 + e] = s;
        }
    } else if (bid < 631) {
        // B-operand frag order: wfrag[ct(48)][kt(8)][lane(64)][8], value =
        // W[ct*16 + (lane&15)][kt*32 + (lane>>4)*8 + j]
        const int flat = (bid - 439) * 256 + tid;   // 0..49151
        const int which = flat / 24576;
        const int rem = flat % 24576;
        const int c = rem >> 9;
        const int kt = (rem >> 6) & 7;
        const int lane = rem & 63;
        const int g = c * 16 + (lane & 15);
        const int k0 = kt * 32 + (lane >> 4) * 8;
        const float* src = (which == 0 ? w_ih : w_hh) + g * 256 + k0;
        bf16_t* dst = (which == 0 ? wfrag_ih : wfrag_hh) + ((c * 8 + kt) * 64 + lane) * 8;
        f32x4 s0 = *(const f32x4*)(src);
        f32x4 s1 = *(const f32x4*)(src + 4);
        bf16x8 o;
        #pragma unroll
        for (int j = 0; j < 4; ++j) { o[j] = (bf16_t)s0[j]; o[4 + j] = (bf16_t)s1[j]; }
        *(bf16x8*)dst = o;
    } else {
        const int g = (bid - 631) * 256 + tid;
        if (g < 512) brz[g] = b_ih[g] + b_hh[g];
    }
}

// ---------------------------------------------------------------------------
// K2: input-side GEMM with fused embedding gather.
// 256 blocks x 512 threads. Block bt owns batch rows [bt*16, bt*16+16),
// loops t=0..31. Wave w owns gate column-tiles {2w,2w+1,16+2w,17+2w,32+2w}
// in registers + {33+2w} in LDS. A-tile gathered into double-buffered LDS.
// Output gi in bf16 C-fragment layout: gi[bt][t][ct(48)][lane(64)][r(4)].
// ---------------------------------------------------------------------------
__global__ void __launch_bounds__(512, 2)
gemm_gi(const int* __restrict__ len_x, const int* __restrict__ ipd_x,
        const float* __restrict__ lenT, const float* __restrict__ ipdT,
        const bf16_t* __restrict__ wfrag_ih, bf16_t* __restrict__ gi) {
    __shared__ bf16_t wlds[8 * 8 * 512];        // 64 KB: per-wave 6th col-tile
    __shared__ bf16_t a_lds[2][8 * 512];        // 2 x 8 KB A-tile staging

    const int tid = threadIdx.x;
    const int lane = tid & 63;
    const int w = tid >> 6;
    const int bt = blockIdx.x;

    const int cts[6] = {2*w, 2*w + 1, 16 + 2*w, 17 + 2*w, 32 + 2*w, 33 + 2*w};

    // weight fragments: 5 col-tiles to registers, 1 to LDS
    bf16x8 wr[5][8];
    #pragma unroll
    for (int cc = 0; cc < 5; ++cc)
        #pragma unroll
        for (int kt = 0; kt < 8; ++kt)
            wr[cc][kt] = *(const bf16x8*)(wfrag_ih + ((cts[cc] * 8 + kt) * 64 + lane) * 8);
    #pragma unroll
    for (int kt = 0; kt < 8; ++kt)
        *(bf16x8*)&wlds[(w * 8 + kt) * 512 + lane * 8] =
            *(const bf16x8*)(wfrag_ih + ((cts[5] * 8 + kt) * 64 + lane) * 8);

    // gather one (16-row, t) A-tile into LDS frag layout
    const int b_row = bt * 16 + (lane & 15);
    const int k0 = w * 32 + (lane >> 4) * 8;   // thread's kt == w here (8 kt x 64 lane)
    const int p = k0 >> 6;
    const int e0 = k0 & 63;
    auto do_gather = [&](int t, int buf) {
        const int seq = t * 4 + p;
        const int v1 = len_x[b_row * SEQN + seq];
        const int v2 = ipd_x[b_row * SEQN + seq];
        const f32x4* lp = (const f32x4*)(lenT + v1 * 64 + e0);
        const f32x4* ip = (const f32x4*)(ipdT + v2 * 64 + e0);
        f32x4 a0 = lp[0] + ip[0];
        f32x4 a1 = lp[1] + ip[1];
        bf16x8 o;
        #pragma unroll
        for (int j = 0; j < 4; ++j) { o[j] = (bf16_t)a0[j]; o[4 + j] = (bf16_t)a1[j]; }
        *(bf16x8*)&a_lds[buf][tid * 8] = o;
    };

    do_gather(0, 0);
    bf16_t* gib = gi + (size_t)bt * 32 * 48 * 256 + lane * 4;

    for (int t = 0; t < TSTEPS; ++t) {
        const int cur = t & 1;
        __syncthreads();                    // a_lds[cur] ready; buf[!cur] free
        if (t + 1 < TSTEPS) do_gather(t + 1, cur ^ 1);

        f32x4 acc[6] = {};
        #pragma unroll
        for (int kt = 0; kt < 8; ++kt) {
            bf16x8 af = *(const bf16x8*)&a_lds[cur][kt * 512 + lane * 8];
            bf16x8 w5 = *(const bf16x8*)&wlds[(w * 8 + kt) * 512 + lane * 8];
            #pragma unroll
            for (int cc = 0; cc < 5; ++cc)
                acc[cc] = MFMA16(af, wr[cc][kt], acc[cc]);
            acc[5] = MFMA16(af, w5, acc[5]);
        }

        #pragma unroll
        for (int cc = 0; cc < 6; ++cc) {
            u16x4 o;
            #pragma unroll
            for (int r = 0; r < 4; ++r) o[r] = f2b(acc[cc][r]);
            *(u16x4*)(gib + ((size_t)t * 48 + cts[cc]) * 256) = o;
        }
    }
}

// ---------------------------------------------------------------------------
// K3: recurrent GRU. 256 blocks x 512 threads; block owns 16 batch rows.
// w_hh register/LDS-resident exactly like K2. h round-trips via 8 KB LDS.
// gi streamed from workspace (bf16 C-frag layout).
// ---------------------------------------------------------------------------
__global__ void __launch_bounds__(512, 2)
gru_kernel(const bf16_t* __restrict__ gi,
           const bf16_t* __restrict__ wfrag_hh,
           const float* __restrict__ brz,
           const float* __restrict__ b_ih,
           const float* __restrict__ b_hh,
           const float* __restrict__ out_w,
           const float* __restrict__ out_b,
           float* __restrict__ out) {
    __shared__ bf16_t wlds[8 * 8 * 512];   // 64 KB
    __shared__ bf16_t h_lds[8 * 512];      // 8 KB, A-frag order for 16 rows
    __shared__ float h_fin[16 * 260];      // 16.6 KB

    const int tid = threadIdx.x;
    const int lane = tid & 63;
    const int w = tid >> 6;
    const int bt = blockIdx.x;
    const int col = lane & 15;
    const int jbase = w * 32;

    const int cts[6] = {2*w, 2*w + 1, 16 + 2*w, 17 + 2*w, 32 + 2*w, 33 + 2*w};

    bf16x8 wr[5][8];
    #pragma unroll
    for (int cc = 0; cc < 5; ++cc)
        #pragma unroll
        for (int kt = 0; kt < 8; ++kt)
            wr[cc][kt] = *(const bf16x8*)(wfrag_hh + ((cts[cc] * 8 + kt) * 64 + lane) * 8);
    #pragma unroll
    for (int kt = 0; kt < 8; ++kt)
        *(bf16x8*)&wlds[(w * 8 + kt) * 512 + lane * 8] =
            *(const bf16x8*)(wfrag_hh + ((cts[5] * 8 + kt) * 64 + lane) * 8);

    // zero initial h
    for (int i = tid; i < 8 * 512; i += 512) h_lds[i] = (bf16_t)0.f;

    // biases
    float b_r[2], b_z[2], b_in[2], b_hn[2];
    #pragma unroll
    for (int c2 = 0; c2 < 2; ++c2) {
        const int j = jbase + c2 * 16 + col;
        b_r[c2] = brz[j];
        b_z[c2] = brz[256 + j];
        b_in[c2] = b_ih[512 + j];
        b_hn[c2] = b_hh[512 + j];
    }

    f32x4 hprev[2] = {};   // [c2], 4 rows each (C-frag)
    const bf16_t* gib = gi + (size_t)bt * 32 * 48 * 256 + lane * 4;

    for (int t = 0; t < TSTEPS; ++t) {
        // stream this step's input gates (overlaps with MFMA below)
        u16x4 g[6];
        #pragma unroll
        for (int cc = 0; cc < 6; ++cc)
            g[cc] = *(const u16x4*)(gib + ((size_t)t * 48 + cts[cc]) * 256);

        f32x4 acc[6] = {};
        __syncthreads();                   // h_lds writes from t-1 visible
        #pragma unroll
        for (int kt = 0; kt < 8; ++kt) {
            bf16x8 ah = *(const bf16x8*)&h_lds[kt * 512 + lane * 8];
            bf16x8 w5 = *(const bf16x8*)&wlds[(w * 8 + kt) * 512 + lane * 8];
            #pragma unroll
            for (int cc = 0; cc < 5; ++cc)
                acc[cc] = MFMA16(ah, wr[cc][kt], acc[cc]);
            acc[5] = MFMA16(ah, w5, acc[5]);
        }
        __syncthreads();                   // all h_lds reads done

        #pragma unroll
        for (int c2 = 0; c2 < 2; ++c2) {
            const int j = jbase + c2 * 16 + col;
            const int kt_j = j >> 5;
            const int lane_j = ((j >> 3) & 3) * 16;
            const int jj = j & 7;
            #pragma unroll
            for (int r = 0; r < 4; ++r) {
                float rg = sigf(acc[c2][r] + b2f(g[c2][r]) + b_r[c2]);
                float zg = sigf(acc[2 + c2][r] + b2f(g[2 + c2][r]) + b_z[c2]);
                float u = b2f(g[4 + c2][r]) + b_in[c2] + rg * (acc[4 + c2][r] + b_hn[c2]);
                float ng = tanh_fast(u);
                float hn = (1.f - zg) * ng + zg * hprev[c2][r];
                hprev[c2][r] = hn;
                const int m = ((lane >> 4) << 2) + r;
                h_lds[kt_j * 512 + (lane_j + m) * 8 + jj] = (bf16_t)hn;
            }
        }
    }

    // Final h -> LDS fp32, then logits = h @ out_w.T + out_b
    #pragma unroll
    for (int c2 = 0; c2 < 2; ++c2) {
        const int j = jbase + c2 * 16 + col;
        #pragma unroll
        for (int r = 0; r < 4; ++r) {
            const int m = ((lane >> 4) << 2) + r;
            h_fin[m * 260 + j] = hprev[c2][r];
        }
    }
    __syncthreads();

    for (int i = tid; i < 16 * NLABELS; i += 512) {
        const int row = i / NLABELS;
        const int cl = i - row * NLABELS;
        const f32x4* wrow = (const f32x4*)(out_w + cl * 256);
        const f32x4* hr = (const f32x4*)(h_fin + row * 260);
        f32x4 acc = {0.f, 0.f, 0.f, 0.f};
        #pragma unroll 4
        for (int k = 0; k < 64; ++k) acc += hr[k] * wrow[k];
        out[(bt * 16 + row) * NLABELS + cl] =
            out_b[cl] + acc[0] + acc[1] + acc[2] + acc[3];
    }
}

// ---------------------------------------------------------------------------
extern "C" void kernel_launch(void* const* d_in, const int* in_sizes, int n_in,
                              void* d_out, int out_size, void* d_ws, size_t ws_size,
                              hipStream_t stream) {
    (void)in_sizes; (void)n_in; (void)out_size; (void)ws_size;
    const int*   len_x   = (const int*)d_in[0];
    const int*   ipd_x   = (const int*)d_in[1];
    const float* len_emb = (const float*)d_in[2];
    const float* ipd_emb = (const float*)d_in[3];
    const float* fc_w    = (const float*)d_in[4];
    const float* fc_b    = (const float*)d_in[5];
    const float* w_ih    = (const float*)d_in[6];
    const float* w_hh    = (const float*)d_in[7];
    const float* b_ih    = (const float*)d_in[8];
    const float* b_hh    = (const float*)d_in[9];
    const float* out_w   = (const float*)d_in[10];
    const float* out_b   = (const float*)d_in[11];

    char* ws = (char*)d_ws;
    float*  lenT = (float*)(ws + OFF_LENT);
    float*  ipdT = (float*)(ws + OFF_IPDT);
    float*  brz  = (float*)(ws + OFF_BRZ);
    bf16_t* wfi  = (bf16_t*)(ws + OFF_WIH);
    bf16_t* wfh  = (bf16_t*)(ws + OFF_WHH);
    bf16_t* gi   = (bf16_t*)(ws + OFF_GI);

    prep_kernel<<<633, 256, 0, stream>>>(len_emb, ipd_emb, fc_w, fc_b,
                                         w_ih, w_hh, b_ih, b_hh,
                                         lenT, ipdT, brz, wfi, wfh);
    gemm_gi<<<256, 512, 0, stream>>>(len_x, ipd_x, lenT, ipdT, wfi, gi);
    gru_kernel<<<256, 512, 0, stream>>>(gi, wfh, brz, b_ih, b_hh,
                                        out_w, out_b, (float*)d_out);
}